// Round 1
// baseline (255.838 us; speedup 1.0000x reference)
//
#include <hip/hip_runtime.h>

typedef __bf16 bf16x8 __attribute__((ext_vector_type(8)));
typedef unsigned short us8 __attribute__((ext_vector_type(8)));
typedef float f32x16 __attribute__((ext_vector_type(16)));

#define N_IMG 32
#define CI 16
#define HH 256
#define WW 256
#define CO 64
#define OHH 254
#define OWW 254

#define XS_W 258   // 256 + 2 (so w up to 257 stays in-array, zero-filled)
#define XS_C 24    // ci padded 16 -> 24 (48B row stride: bank spread + 16B align)
#define WS_K 168   // k padded 160 -> 168 (336B row stride, 16B aligned)

__device__ __forceinline__ unsigned short f2bf(float f) {
  union { float f; unsigned u; } v; v.f = f;
  return (unsigned short)((v.u + 0x7FFFu + ((v.u >> 16) & 1u)) >> 16);  // RNE
}

__device__ __forceinline__ float fast_tanh(float x) {
  float cx = fminf(fmaxf(x, -15.f), 15.f);
  float e = __expf(2.f * cx);
  return (e - 1.f) / (e + 1.f);
}

// One block = one (n, oh) output row (254 pixels, padded to 256).
// Implicit GEMM: D[oc][pixel] = sum_k W[oc][k] * X[k][pixel], k = tap*16 + ci,
// tap = kh*3+kw in [0,9), plus tap 9 = bias column (B = 1 at k=144).
// A-frag (weights): lane m = lane&31 -> oc (+32*mt), k = (lane>>5)*8 + j.
// B-frag (pixels):  lane n = lane&31 -> pixel (+32*nt), same k chunk.
// C/D: col(lane&31) = pixel, row = (reg&3)+8*(reg>>2)+4*(lane>>5) = oc
//   -> min over oc is a pure in-register reduction + one shfl_xor(32).
__global__ __launch_bounds__(256, 2)
void conv_min_tanh(const float* __restrict__ xg, const float* __restrict__ wg,
                   const float* __restrict__ bg, float* __restrict__ out) {
  __shared__ __align__(16) unsigned short xs[3 * XS_W * XS_C];
  __shared__ __align__(16) unsigned short ws[CO * WS_K];

  const int t = threadIdx.x;
  const int n = blockIdx.x / OHH;
  const int oh = blockIdx.x % OHH;

  // ---- stage weights: ws[oc][tap*16+ci] = wg[oc][ci][kh][kw] (bf16) ----
#pragma unroll
  for (int i = 0; i < 36; ++i) {
    int f = i * 256 + t;          // f < 9216, coalesced
    int oc = f / 144;
    int r = f - oc * 144;
    int ci = r / 9;
    int tap = r - ci * 9;
    ws[oc * WS_K + tap * 16 + ci] = f2bf(wg[f]);
  }
  if (t < CO) ws[t * WS_K + 144] = f2bf(bg[t]);      // bias column (tap 9, ci 0)
  for (int i = t; i < CO * 15; i += 256) {           // zero k in [145,160)
    int oc = i / 15;
    ws[oc * WS_K + 145 + (i - oc * 15)] = 0;
  }

  // ---- stage x transposed: xs[kh][w][ci], thread t = w ----
  {
    const size_t base_n = (size_t)n * CI * HH * WW;
#pragma unroll
    for (int kh = 0; kh < 3; ++kh) {
#pragma unroll
      for (int half = 0; half < 2; ++half) {
        float v[8];
#pragma unroll
        for (int j = 0; j < 8; ++j) {   // 8 coalesced row reads (lane = w)
          int ci = half * 8 + j;
          v[j] = xg[base_n + ((size_t)ci * HH + (oh + kh)) * WW + t];
        }
        us8 pk;
#pragma unroll
        for (int j = 0; j < 8; ++j) pk[j] = f2bf(v[j]);
        *(us8*)(xs + (kh * XS_W + t) * XS_C + half * 8) = pk;  // ds_write_b128
      }
    }
  }
  if (t < 96) {                     // zero pad columns w = 256,257
    int kh = t >> 5;
    int rem = t & 31;
    int w = 256 + (rem >> 4);
    int ci = rem & 15;
    xs[(kh * XS_W + w) * XS_C + ci] = 0;
  }
  __syncthreads();

  const int lane = t & 63;
  const int wave = t >> 6;
  const int lr = lane & 31;
  const int qh = lane >> 5;

  // preload all weight fragments (A side): 2 mt x 10 taps x 4 VGPR = 80 VGPRs
  bf16x8 afrag[2][10];
#pragma unroll
  for (int mt = 0; mt < 2; ++mt) {
    const unsigned short* wp = ws + (mt * 32 + lr) * WS_K + qh * 8;
#pragma unroll
    for (int tap = 0; tap < 10; ++tap)
      afrag[mt][tap] = __builtin_bit_cast(bf16x8, *(const us8*)(wp + tap * 16));
  }

  f32x16 acc[2][2];
#pragma unroll
  for (int a = 0; a < 2; ++a)
#pragma unroll
    for (int b = 0; b < 2; ++b)
#pragma unroll
      for (int e = 0; e < 16; ++e) acc[a][b][e] = 0.f;

  // x fragment base: pixel p = wave*64 + nt*32 + lr, addr for w = p + kw
  const unsigned short* xp = xs + (wave * 64 + lr) * XS_C + qh * 8;

#pragma unroll
  for (int tap = 0; tap < 9; ++tap) {
    const int kh = tap / 3, kw = tap - kh * 3;
#pragma unroll
    for (int nt = 0; nt < 2; ++nt) {
      bf16x8 xf = __builtin_bit_cast(
          bf16x8, *(const us8*)(xp + (kh * XS_W + nt * 32 + kw) * XS_C));
      acc[0][nt] = __builtin_amdgcn_mfma_f32_32x32x16_bf16(afrag[0][tap], xf,
                                                           acc[0][nt], 0, 0, 0);
      acc[1][nt] = __builtin_amdgcn_mfma_f32_32x32x16_bf16(afrag[1][tap], xf,
                                                           acc[1][nt], 0, 0, 0);
    }
  }
  {  // bias tap: B = e_{k=144} (1.0 in elem 0 of the qh==0 chunk)
    us8 one = {};
    if (qh == 0) one[0] = 0x3F80;
    bf16x8 xone = __builtin_bit_cast(bf16x8, one);
#pragma unroll
    for (int nt = 0; nt < 2; ++nt) {
      acc[0][nt] = __builtin_amdgcn_mfma_f32_32x32x16_bf16(afrag[0][9], xone,
                                                           acc[0][nt], 0, 0, 0);
      acc[1][nt] = __builtin_amdgcn_mfma_f32_32x32x16_bf16(afrag[1][9], xone,
                                                           acc[1][nt], 0, 0, 0);
    }
  }

  // ---- epilogue: min over ocs (rows) = in-register + one cross-half shfl ----
  float vmin[2];
#pragma unroll
  for (int nt = 0; nt < 2; ++nt) {
    float v = acc[0][nt][0];
#pragma unroll
    for (int e = 1; e < 16; ++e) v = fminf(v, acc[0][nt][e]);
#pragma unroll
    for (int e = 0; e < 16; ++e) v = fminf(v, acc[1][nt][e]);
    v = fminf(v, __shfl_xor(v, 32, 64));  // combine the two oc half-sets
    vmin[nt] = fast_tanh(fast_tanh(v));
  }
  float res = (lane < 32) ? vmin[0] : vmin[1];
  int ow = wave * 64 + lane;   // lane<32: nt=0 pixels; lane>=32: nt=1 pixels
  if (ow < OWW) out[((size_t)n * OHH + oh) * OWW + ow] = res;
}

extern "C" void kernel_launch(void* const* d_in, const int* in_sizes, int n_in,
                              void* d_out, int out_size, void* d_ws, size_t ws_size,
                              hipStream_t stream) {
  const float* x = (const float*)d_in[0];
  const float* w = (const float*)d_in[1];
  const float* b = (const float*)d_in[2];
  float* out = (float*)d_out;
  conv_min_tanh<<<dim3(N_IMG * OHH), dim3(256), 0, stream>>>(x, w, b, out);
}